// Round 6
// baseline (321.743 us; speedup 1.0000x reference)
//
#include <hip/hip_runtime.h>

// Problem constants (match reference)
#define N_NODES_C 100000
#define N_EDGES_C 500000
#define NUM_REL_C 1000
#define E_HID_C   256
#define RPAD      1024   // padded relation count (power of 2 for the scan)

#define NB_SORT   125    // sort blocks; 500000/125 = 4000 edges per block
#define CHUNK_E   (N_EDGES_C / NB_SORT)
#define NB_HIST   250    // k_hist grid when also converting x_e -> bf16
#define XE_F4     (N_NODES_C * E_HID_C / 4)     // 6,400,000 float4
#define CONV_PER_BLK (XE_F4 / NB_HIST)          // 25,600 float4 per block

// ---------------------------------------------------------------------------
// Algebra (validated R1-R5): scatter-softmax cancels (sum of alpha over each
// segment is 1 -> x_type[r] = x_res2_rel[r]); t_c1 is linear so it commutes
// with the per-rel mean. Only per-rel means of raw x_e rows are needed.
//
// Pipeline:
//   memset    : cnt[] = 0 (memset node, not a kernel)
//   k_hist    : per-block LDS histograms -> part[b][r]; atomic cnt[r];
//               blocks also convert x_e -> bf16 table (NT-load x_e so the
//               once-per-call 102 MB read does not evict xb from L3)
//   k_scan    : exclusive prefix sum cnt -> startc (1 block, ~3 us)
//   k_scatter : bucket (src,dst) int2 by relation via LDS cursors; each block
//               derives its own cursor base from startc + column sums of part
//               (coalesced L2 reads, fully parallel -> k_pbase eliminated)
//   k_accum   : per-rel register-accumulated segment sums (16-deep bf16
//               gathers) fused with means + both projections -> rin_t, xt_t
//   k_out     : streaming output assembly; NT loads/stores so the 1 GB
//               stream does not evict the bf16 table from L3 across replays
// ---------------------------------------------------------------------------

typedef float f4 __attribute__((ext_vector_type(4)));

__device__ __forceinline__ unsigned short bf16rne(float f) {
    unsigned u = __float_as_uint(f);
    u += 0x7FFFu + ((u >> 16) & 1u);
    return (unsigned short)(u >> 16);
}

__global__ __launch_bounds__(1024)
void k_hist(const int* __restrict__ rel, const f4* __restrict__ xe4,
            int* __restrict__ part, int* __restrict__ cnt,
            ushort4* __restrict__ xb4, const int do_conv) {
    __shared__ int h[RPAD];
    const int b = blockIdx.x, tid = threadIdx.x;
    const bool hist = (b < NB_SORT);
    if (hist) {
        h[tid] = 0;
        __syncthreads();
        const int base = b * CHUNK_E;
        for (int e = base + tid; e < base + CHUNK_E; e += 1024)
            atomicAdd(&h[rel[e]], 1);
    }
    if (do_conv) {
        const int cb = b * CONV_PER_BLK;
        for (int i = cb + tid; i < cb + CONV_PER_BLK; i += 1024) {
            const f4 v = __builtin_nontemporal_load(&xe4[i]);
            ushort4 o;
            o.x = bf16rne(v.x); o.y = bf16rne(v.y);
            o.z = bf16rne(v.z); o.w = bf16rne(v.w);
            xb4[i] = o;
        }
    }
    if (hist) {
        __syncthreads();
        const int c = h[tid];
        part[b * RPAD + tid] = c;
        if (c) atomicAdd(&cnt[tid], c);
    }
}

__global__ __launch_bounds__(1024)
void k_scan(const int* __restrict__ cnt, int* __restrict__ startc) {
    __shared__ int s[2][RPAD];
    const int t = threadIdx.x;
    const int v = cnt[t];
    s[0][t] = v;
    __syncthreads();
    int cur = 0;
    for (int off = 1; off < RPAD; off <<= 1) {
        const int add = (t >= off) ? s[cur][t - off] : 0;
        s[cur ^ 1][t] = s[cur][t] + add;
        cur ^= 1;
        __syncthreads();
    }
    startc[t] = s[cur][t] - v;
}

__global__ __launch_bounds__(1024)
void k_scatter(const int* __restrict__ edge_index, const int* __restrict__ rel,
               const int* __restrict__ part, const int* __restrict__ startc,
               int2* __restrict__ bpair) {
    __shared__ int cur[RPAD];
    const int b = blockIdx.x, tid = threadIdx.x;
    // cursor base = startc[r] + sum of earlier blocks' partial counts
    // (coalesced 4KB loads per iteration; parallel across all 125 blocks)
    int run = startc[tid];
#pragma unroll 4
    for (int b2 = 0; b2 < b; ++b2) run += part[b2 * RPAD + tid];
    cur[tid] = run;
    __syncthreads();
    const int base = b * CHUNK_E;
    for (int e = base + tid; e < base + CHUNK_E; e += 1024) {
        const int r = rel[e];
        const int pos = atomicAdd(&cur[r], 1);   // LDS atomic, returns old
        bpair[pos] = make_int2(edge_index[e], edge_index[N_EDGES_C + e]);
    }
}

// One block per relation. Waves 0-3 accumulate head (src) quarters, waves 4-7
// tail (dst). 64 edge pairs loaded per wave in ONE coalesced int2 load and
// shfl-broadcast; row gathers issue 16-deep (bf16) / 8-deep (f32 fallback).
// Epilogue: means -> t_c1 projection -> rin row [256] -> s_r1 projection ->
// xt row [128] (= x_res2_rel = x_type for nonempty segments).
template<bool BF16>
__global__ __launch_bounds__(512)
void k_accum(const float* __restrict__ x_e, const unsigned short* __restrict__ xb,
             const int2* __restrict__ bp,
             const int* __restrict__ startc, const int* __restrict__ cnt,
             const float* __restrict__ W_tc1, const float* __restrict__ b_tc1,
             const float* __restrict__ W_sr1, const float* __restrict__ b_sr1,
             float* __restrict__ rin_t,   // [NUM_REL][256]
             float* __restrict__ xt_t)    // [NUM_REL][128]
{
    __shared__ float red[8][E_HID_C];           // 8 KiB
    __shared__ float mh[E_HID_C], mt[E_HID_C], rin[E_HID_C];
    const int r    = blockIdx.x;
    const int tid  = threadIdx.x;
    const int w    = tid >> 6;
    const int lane = tid & 63;
    const int which = w >> 2;               // 0 = head, 1 = tail
    const int q     = w & 3;                // edge quarter
    const int base = startc[r];
    const int c    = cnt[r];
    const int qlen = (c + 3) >> 2;
    const int lo = base + q * qlen;
    const int hi = min(base + c, lo + qlen);

    float4 a = make_float4(0.f, 0.f, 0.f, 0.f);
    for (int g = lo; g < hi; g += 64) {
        const int m = min(64, hi - g);
        int2 pr = make_int2(0, 0);
        if (g + lane < hi) pr = bp[g + lane];
        const int myidx = which ? pr.y : pr.x;
        int k = 0;
        if (BF16) {
            for (; k + 16 <= m; k += 16) {
                uint2 v[16];
#pragma unroll
                for (int u = 0; u < 16; ++u) {
                    const int n = __shfl(myidx, k + u);
                    v[u] = ((const uint2*)(xb + (size_t)n * E_HID_C))[lane];
                }
#pragma unroll
                for (int u = 0; u < 16; ++u) {
                    a.x += __uint_as_float(v[u].x << 16);
                    a.y += __uint_as_float(v[u].x & 0xFFFF0000u);
                    a.z += __uint_as_float(v[u].y << 16);
                    a.w += __uint_as_float(v[u].y & 0xFFFF0000u);
                }
            }
            for (; k < m; ++k) {
                const int n = __shfl(myidx, k);
                const uint2 v = ((const uint2*)(xb + (size_t)n * E_HID_C))[lane];
                a.x += __uint_as_float(v.x << 16);
                a.y += __uint_as_float(v.x & 0xFFFF0000u);
                a.z += __uint_as_float(v.y << 16);
                a.w += __uint_as_float(v.y & 0xFFFF0000u);
            }
        } else {
            for (; k + 8 <= m; k += 8) {
                float4 v[8];
#pragma unroll
                for (int u = 0; u < 8; ++u) {
                    const int n = __shfl(myidx, k + u);
                    v[u] = ((const float4*)(x_e + (size_t)n * E_HID_C))[lane];
                }
#pragma unroll
                for (int u = 0; u < 8; ++u) {
                    a.x += v[u].x; a.y += v[u].y; a.z += v[u].z; a.w += v[u].w;
                }
            }
            for (; k < m; ++k) {
                const int n = __shfl(myidx, k);
                const float4 v = ((const float4*)(x_e + (size_t)n * E_HID_C))[lane];
                a.x += v.x; a.y += v.y; a.z += v.z; a.w += v.w;
            }
        }
    }

    ((float4*)&red[w][0])[lane] = a;
    __syncthreads();

    // means (all 512 threads: wh = head/tail, d = feature)
    {
        const float inv = 1.0f / (float)(c > 0 ? c : 1);
        const int wh = tid >> 8;
        const int d  = tid & 255;
        const float s = red[wh * 4 + 0][d] + red[wh * 4 + 1][d] +
                        red[wh * 4 + 2][d] + red[wh * 4 + 3][d];
        (wh ? mt : mh)[d] = s * inv;
    }
    __syncthreads();

    // t_c1 projection: threads 0..127 -> mean_h @ W_tc1, 128..255 -> mean_t
    if (tid < 256) {
        const int j = tid & 127;
        const float* __restrict__ src = (tid < 128) ? mh : mt;
        float acc = b_tc1[j];
        for (int k = 0; k < E_HID_C; ++k)
            acc += src[k] * W_tc1[k * 128 + j];
        rin[(tid < 128 ? 0 : 128) + j] = acc;   // concat(mean_h, mean_t)
    }
    __syncthreads();

    if (tid < 256) {
        rin_t[(size_t)r * E_HID_C + tid] = rin[tid];
    } else if (tid < 384) {
        const int d = tid - 256;
        float acc = b_sr1[d];
        for (int k = 0; k < E_HID_C; ++k)
            acc += rin[k] * W_sr1[k * 128 + d];
        xt_t[(size_t)r * 128 + d] = acc;
    }
}

// out[e] = [ x_res1[e] + xt[rel[e]] | rin[rel[e]] ]. 8 edges per block; each
// 32-lane group owns one edge. NT load for x_res1 (zero reuse) and NT stores
// for out (streams past L2/L3, keeping the bf16 table resident).
__global__ __launch_bounds__(256)
void k_out(const float* __restrict__ x_res1,
           const int* __restrict__ rel,
           const float* __restrict__ rin_t,
           const float* __restrict__ xt_t,
           float* __restrict__ out)
{
    const f4* __restrict__ xr4  = (const f4*)x_res1;
    const f4* __restrict__ rin4 = (const f4*)rin_t;
    const f4* __restrict__ xt4  = (const f4*)xt_t;
    f4* __restrict__ o4 = (f4*)out;
    const int tid = threadIdx.x;
    const unsigned jj = tid & 31;
    const unsigned e  = blockIdx.x * 8u + (tid >> 5);
    const int r = rel[e];
    const f4 a = __builtin_nontemporal_load(&xr4[(size_t)e * 32 + jj]);
    const f4 t = xt4[(size_t)r * 32 + jj];
    f4* __restrict__ dst = o4 + (size_t)e * 96;
    __builtin_nontemporal_store(a + t, &dst[jj]);
    __builtin_nontemporal_store(rin4[(size_t)r * 64 + jj],      &dst[32 + jj]);
    __builtin_nontemporal_store(rin4[(size_t)r * 64 + 32 + jj], &dst[64 + jj]);
}

// ---------------------------------------------------------------------------
extern "C" void kernel_launch(void* const* d_in, const int* in_sizes, int n_in,
                              void* d_out, int out_size, void* d_ws, size_t ws_size,
                              hipStream_t stream)
{
    const float* x_e    = (const float*)d_in[0];
    const float* x_res1 = (const float*)d_in[1];
    const float* W_tc1  = (const float*)d_in[2];
    const float* b_tc1  = (const float*)d_in[3];
    const float* W_sr1  = (const float*)d_in[4];
    const float* b_sr1  = (const float*)d_in[5];
    // d_in[6]=a1, d_in[7]=a5 unused: scatter-softmax cancels (sum alpha = 1).
    const int* edge_index = (const int*)d_in[8];
    const int* rel        = (const int*)d_in[9];
    // d_in[10] = rel_size = arange(E): identity gather, unused.

    char* ws = (char*)d_ws;
    int*   part   = (int*)  (ws);                  // 125*1024*4 = 512,000 B
    int*   cnt    = (int*)  (ws + 512000);         // 4,096 B
    int*   startc = (int*)  (ws + 516096);         // 4,096 B
    int2*  bpair  = (int2*) (ws + 520192);         // 4,000,000 B
    float* rin_t  = (float*)(ws + 4520192);        // 1,024,000 B
    float* xt_t   = (float*)(ws + 5544192);        // 512,000 B
    unsigned short* xb = (unsigned short*)(ws + 6056192);  // 51,200,000 B
    const size_t need_bf16 = 6056192ull + 51200000ull;     // 57,256,192 B
    const bool use_bf16 = (ws_size >= need_bf16);

    hipMemsetAsync(cnt, 0, RPAD * sizeof(int), stream);
    k_hist   <<<use_bf16 ? NB_HIST : NB_SORT, 1024, 0, stream>>>(
                 rel, (const f4*)x_e, part, cnt,
                 (ushort4*)xb, use_bf16 ? 1 : 0);
    k_scan   <<<1, RPAD, 0, stream>>>(cnt, startc);
    k_scatter<<<NB_SORT, 1024, 0, stream>>>(edge_index, rel, part, startc, bpair);
    if (use_bf16) {
        k_accum<true><<<NUM_REL_C, 512, 0, stream>>>(
            x_e, xb, bpair, startc, cnt,
            W_tc1, b_tc1, W_sr1, b_sr1, rin_t, xt_t);
    } else {
        k_accum<false><<<NUM_REL_C, 512, 0, stream>>>(
            x_e, xb, bpair, startc, cnt,
            W_tc1, b_tc1, W_sr1, b_sr1, rin_t, xt_t);
    }
    k_out    <<<N_EDGES_C / 8, 256, 0, stream>>>(x_res1, rel, rin_t, xt_t,
                                                 (float*)d_out);
}

// Round 7
// 318.406 us; speedup vs baseline: 1.0105x; 1.0105x over previous
//
#include <hip/hip_runtime.h>

// Problem constants (match reference)
#define N_NODES_C 100000
#define N_EDGES_C 500000
#define NUM_REL_C 1000
#define E_HID_C   256
#define RPAD      1024   // padded relation count (power of 2 for the scan)

#define NB_SORT   125    // sort blocks; 500000/125 = 4000 edges per block
#define CHUNK_E   (N_EDGES_C / NB_SORT)
#define NB_HIST   250    // k_hist grid when also converting x_e -> bf16
#define XE_F4     (N_NODES_C * E_HID_C / 4)     // 6,400,000 float4
#define CONV_PER_BLK (XE_F4 / NB_HIST)          // 25,600 float4 per block

// ---------------------------------------------------------------------------
// Algebra (validated R1-R6): scatter-softmax cancels (sum of alpha over each
// segment is 1 -> x_type[r] = x_res2_rel[r]); t_c1 is linear so it commutes
// with the per-rel mean. Only per-rel means of raw x_e rows are needed.
//
// 4-node pipeline (no global atomics, no memset, no dedicated scan node):
//   k_hist    : per-block LDS histograms -> part[b][r]; all blocks also
//               convert x_e -> bf16 table (NT-load x_e)
//   k_scatter : each block reads part column-wise once, accumulating BOTH its
//               cursor base (sum over earlier blocks) and the relation totals;
//               scans totals in LDS (redundant per-block, parallel) -> cursor
//               bases; block 0 publishes startc/cnt for k_accum. Then buckets
//               (src,dst) int2 pairs by relation via LDS cursors.
//   k_accum   : per-rel register-accumulated segment sums (16-deep bf16
//               gathers) fused with means + both projections -> rin_t, xt_t
//   k_out     : streaming output assembly; NT loads/stores so the 1 GB
//               stream does not evict the bf16 table from L3 across replays
// ---------------------------------------------------------------------------

typedef float f4 __attribute__((ext_vector_type(4)));

__device__ __forceinline__ unsigned short bf16rne(float f) {
    unsigned u = __float_as_uint(f);
    u += 0x7FFFu + ((u >> 16) & 1u);
    return (unsigned short)(u >> 16);
}

__global__ __launch_bounds__(1024)
void k_hist(const int* __restrict__ rel, const f4* __restrict__ xe4,
            int* __restrict__ part,
            ushort4* __restrict__ xb4, const int do_conv) {
    __shared__ int h[RPAD];
    const int b = blockIdx.x, tid = threadIdx.x;
    const bool hist = (b < NB_SORT);
    if (hist) {
        h[tid] = 0;
        __syncthreads();
        const int base = b * CHUNK_E;
        for (int e = base + tid; e < base + CHUNK_E; e += 1024)
            atomicAdd(&h[rel[e]], 1);
    }
    if (do_conv) {
        const int cb = b * CONV_PER_BLK;
        for (int i = cb + tid; i < cb + CONV_PER_BLK; i += 1024) {
            const f4 v = __builtin_nontemporal_load(&xe4[i]);
            ushort4 o;
            o.x = bf16rne(v.x); o.y = bf16rne(v.y);
            o.z = bf16rne(v.z); o.w = bf16rne(v.w);
            xb4[i] = o;
        }
    }
    if (hist) {
        __syncthreads();
        part[b * RPAD + tid] = h[tid];
    }
}

__global__ __launch_bounds__(1024)
void k_scatter(const int* __restrict__ edge_index, const int* __restrict__ rel,
               const int* __restrict__ part,
               int* __restrict__ startc, int* __restrict__ cnt,
               int2* __restrict__ bpair) {
    __shared__ int s[2][RPAD];
    __shared__ int cur[RPAD];
    const int b = blockIdx.x, tid = threadIdx.x;

    // One column-wise pass over part: run = sum over blocks before b
    // (this block's cursor offset), total = full per-rel count.
    int run = 0, total = 0;
#pragma unroll 5
    for (int b2 = 0; b2 < NB_SORT; ++b2) {
        const int v = part[b2 * RPAD + tid];
        total += v;
        if (b2 < b) run += v;
    }
    // Redundant-per-block exclusive scan of totals (parallel across blocks).
    s[0][tid] = total;
    __syncthreads();
    int c = 0;
    for (int off = 1; off < RPAD; off <<= 1) {
        const int add = (tid >= off) ? s[c][tid - off] : 0;
        s[c ^ 1][tid] = s[c][tid] + add;
        c ^= 1;
        __syncthreads();
    }
    const int excl = s[c][tid] - total;
    cur[tid] = excl + run;
    if (b == 0) {                   // publish for k_accum (graph-ordered)
        startc[tid] = excl;
        cnt[tid] = total;
    }
    __syncthreads();

    const int base = b * CHUNK_E;
    for (int e = base + tid; e < base + CHUNK_E; e += 1024) {
        const int r = rel[e];
        const int pos = atomicAdd(&cur[r], 1);   // LDS atomic, returns old
        bpair[pos] = make_int2(edge_index[e], edge_index[N_EDGES_C + e]);
    }
}

// One block per relation. Waves 0-3 accumulate head (src) quarters, waves 4-7
// tail (dst). 64 edge pairs loaded per wave in ONE coalesced int2 load and
// shfl-broadcast; row gathers issue 16-deep (bf16) / 8-deep (f32 fallback).
// Epilogue: means -> t_c1 projection -> rin row [256] -> s_r1 projection ->
// xt row [128] (= x_res2_rel = x_type for nonempty segments).
template<bool BF16>
__global__ __launch_bounds__(512)
void k_accum(const float* __restrict__ x_e, const unsigned short* __restrict__ xb,
             const int2* __restrict__ bp,
             const int* __restrict__ startc, const int* __restrict__ cnt,
             const float* __restrict__ W_tc1, const float* __restrict__ b_tc1,
             const float* __restrict__ W_sr1, const float* __restrict__ b_sr1,
             float* __restrict__ rin_t,   // [NUM_REL][256]
             float* __restrict__ xt_t)    // [NUM_REL][128]
{
    __shared__ float red[8][E_HID_C];           // 8 KiB
    __shared__ float mh[E_HID_C], mt[E_HID_C], rin[E_HID_C];
    const int r    = blockIdx.x;
    const int tid  = threadIdx.x;
    const int w    = tid >> 6;
    const int lane = tid & 63;
    const int which = w >> 2;               // 0 = head, 1 = tail
    const int q     = w & 3;                // edge quarter
    const int base = startc[r];
    const int c    = cnt[r];
    const int qlen = (c + 3) >> 2;
    const int lo = base + q * qlen;
    const int hi = min(base + c, lo + qlen);

    float4 a = make_float4(0.f, 0.f, 0.f, 0.f);
    for (int g = lo; g < hi; g += 64) {
        const int m = min(64, hi - g);
        int2 pr = make_int2(0, 0);
        if (g + lane < hi) pr = bp[g + lane];
        const int myidx = which ? pr.y : pr.x;
        int k = 0;
        if (BF16) {
            for (; k + 16 <= m; k += 16) {
                uint2 v[16];
#pragma unroll
                for (int u = 0; u < 16; ++u) {
                    const int n = __shfl(myidx, k + u);
                    v[u] = ((const uint2*)(xb + (size_t)n * E_HID_C))[lane];
                }
#pragma unroll
                for (int u = 0; u < 16; ++u) {
                    a.x += __uint_as_float(v[u].x << 16);
                    a.y += __uint_as_float(v[u].x & 0xFFFF0000u);
                    a.z += __uint_as_float(v[u].y << 16);
                    a.w += __uint_as_float(v[u].y & 0xFFFF0000u);
                }
            }
            for (; k < m; ++k) {
                const int n = __shfl(myidx, k);
                const uint2 v = ((const uint2*)(xb + (size_t)n * E_HID_C))[lane];
                a.x += __uint_as_float(v.x << 16);
                a.y += __uint_as_float(v.x & 0xFFFF0000u);
                a.z += __uint_as_float(v.y << 16);
                a.w += __uint_as_float(v.y & 0xFFFF0000u);
            }
        } else {
            for (; k + 8 <= m; k += 8) {
                float4 v[8];
#pragma unroll
                for (int u = 0; u < 8; ++u) {
                    const int n = __shfl(myidx, k + u);
                    v[u] = ((const float4*)(x_e + (size_t)n * E_HID_C))[lane];
                }
#pragma unroll
                for (int u = 0; u < 8; ++u) {
                    a.x += v[u].x; a.y += v[u].y; a.z += v[u].z; a.w += v[u].w;
                }
            }
            for (; k < m; ++k) {
                const int n = __shfl(myidx, k);
                const float4 v = ((const float4*)(x_e + (size_t)n * E_HID_C))[lane];
                a.x += v.x; a.y += v.y; a.z += v.z; a.w += v.w;
            }
        }
    }

    ((float4*)&red[w][0])[lane] = a;
    __syncthreads();

    // means (all 512 threads: wh = head/tail, d = feature)
    {
        const float inv = 1.0f / (float)(c > 0 ? c : 1);
        const int wh = tid >> 8;
        const int d  = tid & 255;
        const float s = red[wh * 4 + 0][d] + red[wh * 4 + 1][d] +
                        red[wh * 4 + 2][d] + red[wh * 4 + 3][d];
        (wh ? mt : mh)[d] = s * inv;
    }
    __syncthreads();

    // t_c1 projection: threads 0..127 -> mean_h @ W_tc1, 128..255 -> mean_t
    if (tid < 256) {
        const int j = tid & 127;
        const float* __restrict__ src = (tid < 128) ? mh : mt;
        float acc = b_tc1[j];
        for (int k = 0; k < E_HID_C; ++k)
            acc += src[k] * W_tc1[k * 128 + j];
        rin[(tid < 128 ? 0 : 128) + j] = acc;   // concat(mean_h, mean_t)
    }
    __syncthreads();

    if (tid < 256) {
        rin_t[(size_t)r * E_HID_C + tid] = rin[tid];
    } else if (tid < 384) {
        const int d = tid - 256;
        float acc = b_sr1[d];
        for (int k = 0; k < E_HID_C; ++k)
            acc += rin[k] * W_sr1[k * 128 + d];
        xt_t[(size_t)r * 128 + d] = acc;
    }
}

// out[e] = [ x_res1[e] + xt[rel[e]] | rin[rel[e]] ]. 8 edges per block; each
// 32-lane group owns one edge. NT load for x_res1 (zero reuse) and NT stores
// for out (streams past L2/L3, keeping the bf16 table resident).
__global__ __launch_bounds__(256)
void k_out(const float* __restrict__ x_res1,
           const int* __restrict__ rel,
           const float* __restrict__ rin_t,
           const float* __restrict__ xt_t,
           float* __restrict__ out)
{
    const f4* __restrict__ xr4  = (const f4*)x_res1;
    const f4* __restrict__ rin4 = (const f4*)rin_t;
    const f4* __restrict__ xt4  = (const f4*)xt_t;
    f4* __restrict__ o4 = (f4*)out;
    const int tid = threadIdx.x;
    const unsigned jj = tid & 31;
    const unsigned e  = blockIdx.x * 8u + (tid >> 5);
    const int r = rel[e];
    const f4 a = __builtin_nontemporal_load(&xr4[(size_t)e * 32 + jj]);
    const f4 t = xt4[(size_t)r * 32 + jj];
    f4* __restrict__ dst = o4 + (size_t)e * 96;
    __builtin_nontemporal_store(a + t, &dst[jj]);
    __builtin_nontemporal_store(rin4[(size_t)r * 64 + jj],      &dst[32 + jj]);
    __builtin_nontemporal_store(rin4[(size_t)r * 64 + 32 + jj], &dst[64 + jj]);
}

// ---------------------------------------------------------------------------
extern "C" void kernel_launch(void* const* d_in, const int* in_sizes, int n_in,
                              void* d_out, int out_size, void* d_ws, size_t ws_size,
                              hipStream_t stream)
{
    const float* x_e    = (const float*)d_in[0];
    const float* x_res1 = (const float*)d_in[1];
    const float* W_tc1  = (const float*)d_in[2];
    const float* b_tc1  = (const float*)d_in[3];
    const float* W_sr1  = (const float*)d_in[4];
    const float* b_sr1  = (const float*)d_in[5];
    // d_in[6]=a1, d_in[7]=a5 unused: scatter-softmax cancels (sum alpha = 1).
    const int* edge_index = (const int*)d_in[8];
    const int* rel        = (const int*)d_in[9];
    // d_in[10] = rel_size = arange(E): identity gather, unused.

    char* ws = (char*)d_ws;
    int*   part   = (int*)  (ws);                  // 125*1024*4 = 512,000 B
    int*   cnt    = (int*)  (ws + 512000);         // 4,096 B
    int*   startc = (int*)  (ws + 516096);         // 4,096 B
    int2*  bpair  = (int2*) (ws + 520192);         // 4,000,000 B
    float* rin_t  = (float*)(ws + 4520192);        // 1,024,000 B
    float* xt_t   = (float*)(ws + 5544192);        // 512,000 B
    unsigned short* xb = (unsigned short*)(ws + 6056192);  // 51,200,000 B
    const size_t need_bf16 = 6056192ull + 51200000ull;     // 57,256,192 B
    const bool use_bf16 = (ws_size >= need_bf16);

    k_hist   <<<use_bf16 ? NB_HIST : NB_SORT, 1024, 0, stream>>>(
                 rel, (const f4*)x_e, part, (ushort4*)xb, use_bf16 ? 1 : 0);
    k_scatter<<<NB_SORT, 1024, 0, stream>>>(edge_index, rel, part,
                                            startc, cnt, bpair);
    if (use_bf16) {
        k_accum<true><<<NUM_REL_C, 512, 0, stream>>>(
            x_e, xb, bpair, startc, cnt,
            W_tc1, b_tc1, W_sr1, b_sr1, rin_t, xt_t);
    } else {
        k_accum<false><<<NUM_REL_C, 512, 0, stream>>>(
            x_e, xb, bpair, startc, cnt,
            W_tc1, b_tc1, W_sr1, b_sr1, rin_t, xt_t);
    }
    k_out    <<<N_EDGES_C / 8, 256, 0, stream>>>(x_res1, rel, rin_t, xt_t,
                                                 (float*)d_out);
}